// Round 1
// baseline (371.147 us; speedup 1.0000x reference)
//
#include <hip/hip_runtime.h>

// PSAMask collect: out[n, i*65+j, h, w] = x[n, (i-h+64)*129 + (j-w+64), h, w]
// Mask window (129x129, half=64) fully covers the 65x65 offsets -> no masking.
// LDS skew-copy: block per (n, i, h); coalesced trapezoid loads, coalesced row stores.

constexpr int H = 65, W = 65, MH = 129, MW = 129, HALF = 64;
constexpr int HW = H * W;          // 4225
constexpr int PITCH = 66;          // LDS pitch: lane delta (-65) is coprime with 32 banks

__global__ __launch_bounds__(256, 4)
void psamask_collect(const float* __restrict__ x, float* __restrict__ out) {
    __shared__ float lds[MH * PITCH];  // 129*66*4 = 34,056 B

    // Bijective XCD-aware swizzle (nwg = 16900, 16900 % 8 == 4 -> m204 formula)
    constexpr int NWG = 4 * H * H;     // 16900
    constexpr int NX  = 8;
    constexpr int q   = NWG / NX;      // 2112
    constexpr int r   = NWG % NX;      // 4
    int b   = blockIdx.x;
    int xcd = b % NX;
    int idx = b / NX;
    int logical = (xcd < r ? xcd * (q + 1) : r * (q + 1) + (xcd - r) * q) + idx;

    // logical -> (n, i, h), h innermost so h-neighbors (shared output lines) co-locate
    int n   = logical / (H * H);
    int rem = logical - n * (H * H);
    int i   = rem / H;
    int h   = rem - i * H;
    int Mh  = i - h + HALF;            // always in [0, 128]

    const float* src = x + ((size_t)n * (MH * MW) + (size_t)Mh * MW) * HW + (size_t)h * W;

    // Load trapezoid: row u used for w in [max(0,64-u), min(65,129-u))
    int wave = threadIdx.x >> 6;
    int lane = threadIdx.x & 63;
    for (int u = wave; u < MH; u += 4) {
        int lo = HALF - u; if (lo < 0) lo = 0;
        int hi = MH - u;   if (hi > W) hi = W;
        const float* rowp = src + (size_t)u * HW;
        for (int w = lo + lane; w < hi; w += 64) {
            lds[u * PITCH + w] = rowp[w];
        }
    }
    __syncthreads();

    // Store: out row (i*W+j, h, :) <- skewed LDS read, coalesced 65-float writes
    float* dst = out + (size_t)n * HW * HW + (size_t)i * W * HW + (size_t)h * W;
    for (int f = threadIdx.x; f < W * W; f += 256) {
        int j = f / W;
        int w = f - j * W;
        dst[(size_t)j * HW + w] = lds[(j - w + HALF) * PITCH + w];
    }
}

extern "C" void kernel_launch(void* const* d_in, const int* in_sizes, int n_in,
                              void* d_out, int out_size, void* d_ws, size_t ws_size,
                              hipStream_t stream) {
    const float* x = (const float*)d_in[0];
    float* out = (float*)d_out;
    (void)in_sizes; (void)n_in; (void)out_size; (void)d_ws; (void)ws_size;
    psamask_collect<<<dim3(4 * H * H), dim3(256), 0, stream>>>(x, out);
}

// Round 2
// 164.233 us; speedup vs baseline: 2.2599x; 2.2599x over previous
//
#include <hip/hip_runtime.h>

// PSAMask collect: out[n, i*65+j, h, w] = x[n, (i-h+64)*129 + (j-w+64), h, w]
// Mask window fully covers offsets -> pure gather, no masking.
// Block per (n,i,h): async global->LDS trapezoid staging, skewed LDS reads,
// coalesced row stores. LDS pitch 66 -> conflict-free skew reads.

constexpr int H = 65, W = 65, MH = 129, MW = 129, HALF = 64;
constexpr int HW = H * W;          // 4225
constexpr int PITCH = 66;          // lane delta on skew read = -65 -> distinct banks

__global__ __launch_bounds__(512, 4)
void psamask_collect(const float* __restrict__ x, float* __restrict__ out) {
    __shared__ float lds[MH * PITCH];  // 34,056 B -> 4 blocks/CU, 32 waves/CU

    // Bijective XCD-aware swizzle (nwg=16900, 16900%8==4 -> m204 formula)
    constexpr int NWG = 4 * H * H;
    constexpr int NX  = 8;
    constexpr int q   = NWG / NX;
    constexpr int r   = NWG % NX;
    int b   = blockIdx.x;
    int xcd = b % NX;
    int idx = b / NX;
    int logical = (xcd < r ? xcd * (q + 1) : r * (q + 1) + (xcd - r) * q) + idx;

    // h innermost: consecutive blocks write adjacent 260B output segments
    // (same L2 lines at boundaries -> full-line write combining)
    int n   = logical / (H * H);
    int rem = logical - n * (H * H);
    int i   = rem / H;
    int h   = rem - i * H;
    int Mh  = i - h + HALF;            // always in [0, 128]

    const float* src = x + (size_t)(n * (MH * MW) + Mh * MW) * HW + h * W;

    int wave = threadIdx.x >> 6;
    int lane = threadIdx.x & 63;
    // Async staging: row u used for w in [max(0,64-u), min(65,129-u)).
    // All loads issue with no intermediate waitcnt; __syncthreads drains vmcnt.
    for (int u = wave; u < MH; u += 8) {
        int lo = HALF - u; if (lo < 0) lo = 0;
        int hi = MH - u;   if (hi > W) hi = W;
        const float* rowp = src + (size_t)u * HW;
        for (int w0 = lo; w0 < hi; w0 += 64) {
            int w = w0 + lane;
            if (w < hi) {
                // LDS dest: wave-uniform base (u,w0 uniform) + lane*4 == lds[u*PITCH+w]
                __builtin_amdgcn_global_load_lds(
                    (const __attribute__((address_space(1))) unsigned int*)(rowp + w),
                    (__attribute__((address_space(3))) unsigned int*)(&lds[u * PITCH + w0]),
                    4, 0, 0);
            }
        }
    }
    __syncthreads();

    // Store: out row (i*W+j, h, :) <- skewed LDS read, coalesced 65-float rows
    float* dst = out + (size_t)n * HW * HW + (size_t)(i * W) * HW + h * W;
    for (int f = threadIdx.x; f < W * W; f += 512) {
        int j = f / W;
        int w = f - j * W;
        dst[(size_t)j * HW + w] = lds[(j - w + HALF) * PITCH + w];
    }
}

extern "C" void kernel_launch(void* const* d_in, const int* in_sizes, int n_in,
                              void* d_out, int out_size, void* d_ws, size_t ws_size,
                              hipStream_t stream) {
    const float* x = (const float*)d_in[0];
    float* out = (float*)d_out;
    (void)in_sizes; (void)n_in; (void)out_size; (void)d_ws; (void)ws_size;
    psamask_collect<<<dim3(4 * H * H), dim3(512), 0, stream>>>(x, out);
}